// Round 4
// baseline (914.707 us; speedup 1.0000x reference)
//
#include <hip/hip_runtime.h>
#include <hip/hip_bf16.h>

#define M_TOT 16384
#define N_TOT 4096
#define K_TOT 4096

typedef __attribute__((ext_vector_type(8))) short bf16x8;
typedef __attribute__((ext_vector_type(4))) float f32x4;

typedef const __attribute__((address_space(1))) void* gptr_t;
typedef __attribute__((address_space(3))) void* lptr_t;

__device__ inline unsigned short f2bf(float f) {
    union { float f; unsigned u; } v; v.f = f;
    unsigned u = v.u;
    u += 0x7FFFu + ((u >> 16) & 1u);   // RNE
    return (unsigned short)(u >> 16);
}

__device__ inline unsigned short sgn_bf(float f) {
    union { float f; unsigned u; } v; v.f = f;
    // bf16 +-1.0 : sign | 0x3F80
    return (unsigned short)(((v.u >> 16) & 0x8000u) | 0x3F80u);
}

// ---------------------------------------------------------------------------
// Kernel 1: per-row scale = mean(|W|), binarize W -> bf16 +-1
// ---------------------------------------------------------------------------
__global__ void prep_weight(const float* __restrict__ w,
                            unsigned short* __restrict__ bw,  // may be null
                            float* __restrict__ scale) {
    const int row = blockIdx.x;
    const int tid = threadIdx.x;
    const float4* wr = (const float4*)(w + (size_t)row * K_TOT);
    float s = 0.f;
#pragma unroll
    for (int i = 0; i < 4; ++i) {
        int idx = tid + i * 256;            // float4 index 0..1023
        float4 v = wr[idx];
        s += fabsf(v.x) + fabsf(v.y) + fabsf(v.z) + fabsf(v.w);
        if (bw) {
            ushort4 b;
            b.x = sgn_bf(v.x); b.y = sgn_bf(v.y);
            b.z = sgn_bf(v.z); b.w = sgn_bf(v.w);
            *(ushort4*)(bw + (size_t)row * K_TOT + idx * 4) = b;
        }
    }
#pragma unroll
    for (int off = 32; off > 0; off >>= 1) s += __shfl_down(s, off, 64);
    __shared__ float red[4];
    if ((tid & 63) == 0) red[tid >> 6] = s;
    __syncthreads();
    if (tid == 0) scale[row] = (red[0] + red[1] + red[2] + red[3]) * (1.f / (float)K_TOT);
}

// ---------------------------------------------------------------------------
// Kernel 2: x fp32 -> bf16  (2x float4 in, one 16B uint4 out per lane/iter)
// ---------------------------------------------------------------------------
__global__ void conv_x(const float* __restrict__ x, unsigned int* __restrict__ xb) {
    const long n = (long)M_TOT * K_TOT / 8;   // ushort8 units
    long i = (long)blockIdx.x * blockDim.x + threadIdx.x;
    const long stride = (long)gridDim.x * blockDim.x;
    const float4* x4 = (const float4*)x;
    for (; i < n; i += stride) {
        float4 a = x4[2 * i];
        float4 b = x4[2 * i + 1];
        uint4 o;
        o.x = ((unsigned)f2bf(a.y) << 16) | f2bf(a.x);
        o.y = ((unsigned)f2bf(a.w) << 16) | f2bf(a.z);
        o.z = ((unsigned)f2bf(b.y) << 16) | f2bf(b.x);
        o.w = ((unsigned)f2bf(b.w) << 16) | f2bf(b.z);
        ((uint4*)xb)[i] = o;
    }
}

// ---------------------------------------------------------------------------
// Kernel 3 (fast path): 256x256 8-phase GEMM (m201 template, full depth-3).
// 8 waves (2M x 4N), BK=64, 2 K-tiles per iteration, 8 phases/iter.
// LDS 128 KiB: [AS0 | BS0 | AS1 | BS1], each 256x64 bf16 (32 KiB).
// 3-bit swizzle: byte ^= ((byte>>7)&7)<<4 (conflict-free ds_read_b128,
// verified R2: SQ_LDS_BANK_CONFLICT = 0). Inverse-swizzled global source.
// Staging timed so each consumed half-tile is issued >=3 phases before its
// wait -> steady-state vmcnt(6) at P3/P7 (3 half-tiles in flight, m201
// depth). Liveness ledger:
//   A-buf0 read P0,P2  -> staged h0@P3, h1@P4
//   B-buf0 read P0,P1  -> staged h0@P2, h1@P3
//   A-buf1 read P4,P6  -> staged h0@P7(prev), h1@P0
//   B-buf1 read P4,P5  -> staged h0@P6, h1@P7
// vmcnt ledger (steady state, 14 issued/iter):
//   P3 vm6 drains {prevP6:2, prevP7:4, P0:2} = buf1 tile; keeps {P2:2,P3:4}
//   P7 vm6 drains {P3:4, P4:2} = buf0 tile;  keeps {P6:2, P7:4}
// ---------------------------------------------------------------------------
#define AS0 0
#define BS0 16384
#define AS1 32768
#define BS1 49152

// stage one half-tile (128 rows x 64 cols) = 2 global_load_lds calls.
// LDS dest is linear; global source col is pre-swizzled (involution).
#define STAGE(Mat, row0, ldsbase, h, ktv)                                         \
  {                                                                               \
    _Pragma("unroll")                                                             \
    for (int c_ = 0; c_ < 2; ++c_) {                                              \
      const unsigned short* g_ = (Mat) +                                          \
          (size_t)((row0) + (h)*128 + c_*64 + wv*8 + srow) * K_TOT + (ktv) + scol;\
      __builtin_amdgcn_global_load_lds((gptr_t)g_,                                \
          (lptr_t)(lds + (ldsbase) + ((h)*128 + c_*64 + wv*8) * 64), 16, 0, 0);   \
    }                                                                             \
  }

// A fragments for M-half h: 8 x ds_read_b128 (swizzled addresses)
#define DS_A(h, base)                                                             \
  {                                                                               \
    _Pragma("unroll")                                                             \
    for (int i_ = 0; i_ < 4; ++i_) {                                              \
      _Pragma("unroll")                                                           \
      for (int k_ = 0; k_ < 2; ++k_) {                                            \
        int off_ = (wr*128 + (h)*64 + i_*16 + l16)*128 + k_*64 + quad*16;         \
        off_ ^= ((off_ >> 7) & 7) << 4;                                           \
        af[i_][k_] = *(const bf16x8*)((const char*)(lds + (base)) + off_);        \
      }                                                                           \
    }                                                                             \
  }

// B fragments for N-quarter pair g: 4 x ds_read_b128
#define DS_B(dst, g, base)                                                        \
  {                                                                               \
    _Pragma("unroll")                                                             \
    for (int j_ = 0; j_ < 2; ++j_) {                                              \
      _Pragma("unroll")                                                           \
      for (int k_ = 0; k_ < 2; ++k_) {                                            \
        int ob_ = (wc*64 + (g)*32 + j_*16 + l16)*128 + k_*64 + quad*16;           \
        ob_ ^= ((ob_ >> 7) & 7) << 4;                                             \
        dst[j_][k_] = *(const bf16x8*)((const char*)(lds + (base)) + ob_);        \
      }                                                                           \
    }                                                                             \
  }

// one C-quadrant x K=64 : 16 MFMA, setprio-wrapped
#define MMA(h, g, bset)                                                           \
  {                                                                               \
    __builtin_amdgcn_s_setprio(1);                                                \
    _Pragma("unroll")                                                             \
    for (int i_ = 0; i_ < 4; ++i_) {                                              \
      _Pragma("unroll")                                                           \
      for (int j_ = 0; j_ < 2; ++j_) {                                            \
        acc[(h)*4+i_][(g)*2+j_] = __builtin_amdgcn_mfma_f32_16x16x32_bf16(        \
            af[i_][0], bset[j_][0], acc[(h)*4+i_][(g)*2+j_], 0, 0, 0);            \
        acc[(h)*4+i_][(g)*2+j_] = __builtin_amdgcn_mfma_f32_16x16x32_bf16(        \
            af[i_][1], bset[j_][1], acc[(h)*4+i_][(g)*2+j_], 0, 0, 0);            \
      }                                                                           \
    }                                                                             \
    __builtin_amdgcn_s_setprio(0);                                                \
  }

#define BAR1  { __builtin_amdgcn_s_barrier(); asm volatile("s_waitcnt lgkmcnt(0)"); }
#define BAR2  { __builtin_amdgcn_s_barrier(); }
#define VM6   { asm volatile("s_waitcnt vmcnt(6)" ::: "memory"); }
#define VM0   { asm volatile("s_waitcnt vmcnt(0)" ::: "memory"); }

__global__ __launch_bounds__(512, 2) void gemm_bin_8ph(
    const unsigned short* __restrict__ A,
    const unsigned short* __restrict__ B,
    const float* __restrict__ scale,
    const float* __restrict__ bias,
    float* __restrict__ out) {
    __shared__ unsigned short lds[4 * 16384];   // 128 KiB

    const int tid  = threadIdx.x;
    const int wv   = tid >> 6;        // 0..7
    const int lane = tid & 63;
    const int quad = lane >> 4;
    const int l16  = lane & 15;
    const int wr   = wv >> 2;         // 0..1  (M)
    const int wc   = wv & 3;          // 0..3  (N)

    // XCD-aware bijective swizzle: nwg = 1024, 1024/8 = 128 per XCD
    int bid = blockIdx.x;
    bid = (bid & 7) * 128 + (bid >> 3);
    const int bn = (bid & 15) * 256;  // N_TOT/256 = 16
    const int bm = (bid >> 4) * 256;

    // staging lane -> (row, pre-swizzled col): inverse of the 3-bit XOR.
    // lane l writes LDS slot (l&7) of row (l>>3); it must carry the data of
    // unswizzled slot (l&7)^((l>>3)&7)  (involution within the 8-row group).
    const int srow = lane >> 3;                                     // 0..7
    const int scol = (((lane & 7) ^ ((lane >> 3) & 7)) * 8);        // elements

    f32x4 acc[8][4] = {};
    bf16x8 af[4][2], bl[2][2], bh[2][2];

    // ---- prologue: buf0 tile0 full (8) + "prev-P6/P7" roles for buf1 (6) ----
    STAGE(A, bm, AS0, 0, 0)
    STAGE(A, bm, AS0, 1, 0)
    STAGE(B, bn, BS0, 0, 0)
    STAGE(B, bn, BS0, 1, 0)
    STAGE(B, bn, BS1, 0, 64)    // P6-role
    STAGE(A, bm, AS1, 0, 64)    // P7-role
    STAGE(B, bn, BS1, 1, 64)    // P7-role
    VM6                          // buf0 tile0 landed; 6 buf1 loads in flight
    __builtin_amdgcn_s_barrier();

    int kt = 0;
#pragma unroll 1
    for (int t = 0; t < (K_TOT / 128) - 1; ++t, kt += 128) {
        // P0: read buf0 a(h0),b_lo; stage A->buf1 h1 @ kt+64 (read at P6)
        DS_A(0, AS0) DS_B(bl, 0, BS0)
        STAGE(A, bm, AS1, 1, kt + 64)
        BAR1 MMA(0, 0, bl) BAR2
        // P1: read buf0 b_hi
        DS_B(bh, 1, BS0)
        BAR1 MMA(0, 1, bh) BAR2
        // P2: read buf0 a(h1); stage B->buf0 h0 @ kt+128 (B buf0 free after P1)
        DS_A(1, AS0)
        STAGE(B, bn, BS0, 0, kt + 128)
        BAR1 MMA(1, 1, bh) BAR2
        // P3: stage A->buf0 h0, B->buf0 h1 @ kt+128 (A buf0 free after P2);
        //     wait buf1 complete (youngest = P0's A1h1, 3 phases old)
        STAGE(A, bm, AS0, 0, kt + 128)
        STAGE(B, bn, BS0, 1, kt + 128)
        BAR1 MMA(1, 0, bl) VM6 BAR2
        // P4: read buf1 a(h0),b_lo; stage A->buf0 h1 @ kt+128
        DS_A(0, AS1) DS_B(bl, 0, BS1)
        STAGE(A, bm, AS0, 1, kt + 128)
        BAR1 MMA(0, 0, bl) BAR2
        // P5: read buf1 b_hi
        DS_B(bh, 1, BS1)
        BAR1 MMA(0, 1, bh) BAR2
        // P6: read buf1 a(h1); stage B->buf1 h0 @ kt+192 (B buf1 free after P5)
        DS_A(1, AS1)
        STAGE(B, bn, BS1, 0, kt + 192)
        BAR1 MMA(1, 1, bh) BAR2
        // P7: stage A->buf1 h0, B->buf1 h1 @ kt+192 (A buf1 free after P6);
        //     wait buf0 next tile complete (youngest = P4's A0h1)
        STAGE(A, bm, AS1, 0, kt + 192)
        STAGE(B, bn, BS1, 1, kt + 192)
        BAR1 MMA(1, 0, bl) VM6 BAR2
    }

    // ---- peeled last iteration (kt = K_TOT-128): only A1h1 still staged ----
    DS_A(0, AS0) DS_B(bl, 0, BS0)
    STAGE(A, bm, AS1, 1, kt + 64)
    BAR1 MMA(0, 0, bl) BAR2
    DS_B(bh, 1, BS0)
    BAR1 MMA(0, 1, bh) BAR2
    DS_A(1, AS0)
    BAR1 MMA(1, 1, bh) BAR2
    BAR1 MMA(1, 0, bl) VM0 BAR2      // drain: all 8 outstanding buf1 loads
    DS_A(0, AS1) DS_B(bl, 0, BS1)
    BAR1 MMA(0, 0, bl) BAR2
    DS_B(bh, 1, BS1)
    BAR1 MMA(0, 1, bh) BAR2
    DS_A(1, AS1)
    BAR1 MMA(1, 1, bh) BAR2
    BAR1 MMA(1, 0, bl)

    // ---- epilogue: C/D layout col=l16, row=quad*4+reg (verified m89/m91) ----
#pragma unroll
    for (int j4 = 0; j4 < 4; ++j4) {
        const int gn = bn + wc * 64 + j4 * 16 + l16;
        const float sc = scale[gn];
        const float bi = bias[gn];
#pragma unroll
        for (int i8 = 0; i8 < 8; ++i8) {
            const int gm0 = bm + wr * 128 + i8 * 16 + quad * 4;
#pragma unroll
            for (int r = 0; r < 4; ++r)
                out[(size_t)(gm0 + r) * N_TOT + gn] = acc[i8][j4][r] * sc + bi;
        }
    }
}

// ---------------------------------------------------------------------------
// Fallback (ws too small): fp32 inputs, inline convert, padded LDS
// ---------------------------------------------------------------------------
__global__ __launch_bounds__(256) void gemm_bin_fb(const float* __restrict__ A,
                                                   const float* __restrict__ Bf,
                                                   const float* __restrict__ scale,
                                                   const float* __restrict__ bias,
                                                   float* __restrict__ out) {
    __shared__ unsigned short As[128][40];
    __shared__ unsigned short Bs[128][40];

    const int tid  = threadIdx.x;
    const int wave = tid >> 6;
    const int lane = tid & 63;
    const int quad = lane >> 4;
    const int l16  = lane & 15;
    const int wr   = wave >> 1;
    const int wc   = wave & 1;
    const int bn   = blockIdx.x * 128;
    const int bm   = blockIdx.y * 128;

    f32x4 acc[4][4] = {};

    for (int kt = 0; kt < K_TOT; kt += 32) {
        const int row0 = tid >> 3;
        const int c4   = (tid & 7) * 4;
#pragma unroll
        for (int p = 0; p < 4; ++p) {
            int row = row0 + p * 32;
            float4 v = *(const float4*)(A + (size_t)(bm + row) * K_TOT + kt + c4);
            ushort4 b;
            b.x = f2bf(v.x); b.y = f2bf(v.y); b.z = f2bf(v.z); b.w = f2bf(v.w);
            *(ushort4*)&As[row][c4] = b;
        }
#pragma unroll
        for (int p = 0; p < 4; ++p) {
            int row = row0 + p * 32;
            float4 v = *(const float4*)(Bf + (size_t)(bn + row) * K_TOT + kt + c4);
            ushort4 b;
            b.x = sgn_bf(v.x); b.y = sgn_bf(v.y);
            b.z = sgn_bf(v.z); b.w = sgn_bf(v.w);
            *(ushort4*)&Bs[row][c4] = b;
        }
        __syncthreads();

        bf16x8 af2[4], bfr[4];
#pragma unroll
        for (int i = 0; i < 4; ++i)
            af2[i] = *(const bf16x8*)&As[wr * 64 + i * 16 + l16][quad * 8];
#pragma unroll
        for (int j = 0; j < 4; ++j)
            bfr[j] = *(const bf16x8*)&Bs[wc * 64 + j * 16 + l16][quad * 8];
#pragma unroll
        for (int i = 0; i < 4; ++i)
#pragma unroll
            for (int j = 0; j < 4; ++j)
                acc[i][j] = __builtin_amdgcn_mfma_f32_16x16x32_bf16(af2[i], bfr[j], acc[i][j], 0, 0, 0);
        __syncthreads();
    }

#pragma unroll
    for (int j = 0; j < 4; ++j) {
        const int gn = bn + wc * 64 + j * 16 + l16;
        const float sc = scale[gn];
        const float bi = bias[gn];
#pragma unroll
        for (int i = 0; i < 4; ++i) {
            const int gm0 = bm + wr * 64 + i * 16 + quad * 4;
#pragma unroll
            for (int r = 0; r < 4; ++r)
                out[(size_t)(gm0 + r) * N_TOT + gn] = acc[i][j][r] * sc + bi;
        }
    }
}

// ---------------------------------------------------------------------------
extern "C" void kernel_launch(void* const* d_in, const int* in_sizes, int n_in,
                              void* d_out, int out_size, void* d_ws, size_t ws_size,
                              hipStream_t stream) {
    const float* x    = (const float*)d_in[0];
    const float* w    = (const float*)d_in[1];
    const float* bias = (const float*)d_in[2];
    float* out        = (float*)d_out;

    // ws layout: [scale 16KB][bw 32MB][xb 128MB]
    const size_t off_scale = 0;
    const size_t off_bw    = 16384;
    const size_t off_xb    = off_bw + (size_t)N_TOT * K_TOT * 2;
    const size_t need_full = off_xb + (size_t)M_TOT * K_TOT * 2;

    float* scale = (float*)((char*)d_ws + off_scale);
    const bool full = ws_size >= need_full;

    if (full) {
        unsigned short* bw = (unsigned short*)((char*)d_ws + off_bw);
        unsigned short* xb = (unsigned short*)((char*)d_ws + off_xb);
        prep_weight<<<N_TOT, 256, 0, stream>>>(w, bw, scale);
        conv_x<<<4096, 256, 0, stream>>>(x, (unsigned int*)xb);
        const int nwg = (M_TOT / 256) * (N_TOT / 256);   // 64 * 16 = 1024
        gemm_bin_8ph<<<nwg, 512, 0, stream>>>(xb, bw, scale, bias, out);
    } else {
        prep_weight<<<N_TOT, 256, 0, stream>>>(w, nullptr, scale);
        dim3 grid(N_TOT / 128, M_TOT / 128);
        gemm_bin_fb<<<grid, 256, 0, stream>>>(x, w, scale, bias, out);
    }
}